// Round 1
// baseline (333.103 us; speedup 1.0000x reference)
//
#include <hip/hip_runtime.h>
#include <cstdint>
#include <cstddef>

// Problem constants (B,S,E fixed by the reference; H=16 heads, D=64)
#define B_ 8
#define S_ 1024
#define E_ 1024
#define H_ 16
#define D_ 64
#define M_ (B_*S_)   // 8192 rows of x

typedef __bf16 bf16;
typedef float  f32;
typedef __attribute__((ext_vector_type(8))) __bf16 bf16x8;
typedef __attribute__((ext_vector_type(4))) __bf16 bf16x4;
typedef __attribute__((ext_vector_type(4))) float  f32x4;

__device__ __forceinline__ f32x4 mfma16(bf16x8 a, bf16x8 b, f32x4 c) {
  return __builtin_amdgcn_mfma_f32_16x16x32_bf16(a, b, c, 0, 0, 0);
}

// ---------------------------------------------------------------------------
// Kernel 1: transpose + split-convert a 1024x1024 fp32 weight into bf16
// hi/lo buffers, laid out transposed ([f][e]) so GEMM B-fragments are
// contiguous-in-k.  lo == nullptr -> only hi (used for W_Value).
// ---------------------------------------------------------------------------
__global__ __launch_bounds__(512) void wt_conv_kernel(
    const float* __restrict__ W, bf16* __restrict__ hi, bf16* __restrict__ lo) {
  __shared__ float t[64][65];
  const int f0 = blockIdx.x * 64, e0 = blockIdx.y * 64;
  const int tx = threadIdx.x, ty = threadIdx.y;
#pragma unroll
  for (int j = 0; j < 8; ++j)
    t[ty + 8 * j][tx] = W[(size_t)(e0 + ty + 8 * j) * E_ + f0 + tx];
  __syncthreads();
#pragma unroll
  for (int j = 0; j < 8; ++j) {
    float v = t[tx][ty + 8 * j];
    bf16 hh = (bf16)v;
    size_t idx = (size_t)(f0 + ty + 8 * j) * E_ + e0 + tx;
    hi[idx] = hh;
    if (lo) lo[idx] = (bf16)(v - (float)hh);
  }
}

// ---------------------------------------------------------------------------
// Kernel 2: split-precision GEMM  O = X(fp32) * W  (W given transposed, hi/lo)
// 3-term bf16 split => ~fp32-accurate scores downstream.
// Output written as hi/lo bf16 in [B,H,S,D] layout.
// Tile: BM=128, BN=128, BK=32, 4 waves (2x2), each wave 64x64 (4x4 16x16 frags)
// ---------------------------------------------------------------------------
__global__ __launch_bounds__(256) void gemm_qk_kernel(
    const float* __restrict__ X, const bf16* __restrict__ Bth,
    const bf16* __restrict__ Btl, bf16* __restrict__ Oh, bf16* __restrict__ Ol) {
  __shared__ bf16 sAh[128][40], sAl[128][40], sBh[128][40], sBl[128][40];
  const int n0 = blockIdx.x * 128, m0 = blockIdx.y * 128;
  const int tid = threadIdx.x;
  const int lane = tid & 63, w = tid >> 6;
  const int wm = (w >> 1) * 64, wn = (w & 1) * 64;
  const int fr = lane & 15, fg = lane >> 4, ko = fg * 8;
  f32x4 acc[4][4] = {};
  for (int k0 = 0; k0 < E_; k0 += 32) {
    __syncthreads();
    // stage A: fp32 x tile -> split bf16 hi/lo
#pragma unroll
    for (int i = 0; i < 4; ++i) {
      int lin = (tid + i * 256) * 4;
      int r = lin >> 5, c = lin & 31;
      f32x4 v = *(const f32x4*)&X[(size_t)(m0 + r) * E_ + k0 + c];
      bf16x4 hv, lv;
#pragma unroll
      for (int j = 0; j < 4; ++j) {
        bf16 hh = (bf16)v[j];
        hv[j] = hh;
        lv[j] = (bf16)(v[j] - (float)hh);
      }
      *(bf16x4*)&sAh[r][c] = hv;
      *(bf16x4*)&sAl[r][c] = lv;
    }
    // stage B: pre-converted transposed weight tiles (bf16 hi/lo)
#pragma unroll
    for (int i = 0; i < 2; ++i) {
      int lin = (tid + i * 256) * 8;
      int r = lin >> 5, c = lin & 31;
      *(bf16x8*)&sBh[r][c] = *(const bf16x8*)&Bth[(size_t)(n0 + r) * E_ + k0 + c];
      *(bf16x8*)&sBl[r][c] = *(const bf16x8*)&Btl[(size_t)(n0 + r) * E_ + k0 + c];
    }
    __syncthreads();
    bf16x8 ah[4], al[4];
#pragma unroll
    for (int mi = 0; mi < 4; ++mi) {
      ah[mi] = *(const bf16x8*)&sAh[wm + mi * 16 + fr][ko];
      al[mi] = *(const bf16x8*)&sAl[wm + mi * 16 + fr][ko];
    }
#pragma unroll
    for (int ni = 0; ni < 4; ++ni) {
      bf16x8 bh = *(const bf16x8*)&sBh[wn + ni * 16 + fr][ko];
      bf16x8 bl = *(const bf16x8*)&sBl[wn + ni * 16 + fr][ko];
#pragma unroll
      for (int mi = 0; mi < 4; ++mi) {
        acc[mi][ni] = mfma16(ah[mi], bh, acc[mi][ni]);
        acc[mi][ni] = mfma16(ah[mi], bl, acc[mi][ni]);
        acc[mi][ni] = mfma16(al[mi], bh, acc[mi][ni]);
      }
    }
  }
  // epilogue: split fp32 acc -> hi/lo bf16, scatter to [B,H,S,D]
#pragma unroll
  for (int mi = 0; mi < 4; ++mi)
#pragma unroll
    for (int ni = 0; ni < 4; ++ni)
#pragma unroll
      for (int r = 0; r < 4; ++r) {
        int row = m0 + wm + mi * 16 + fg * 4 + r;   // = b*1024 + s
        int col = n0 + wn + ni * 16 + fr;           // = hd*64 + d
        float v = acc[mi][ni][r];
        int bb = row >> 10, s = row & 1023;
        int hd = col >> 6, d = col & 63;
        size_t idx = ((size_t)(bb * H_ + hd) * S_ + s) * D_ + d;
        bf16 hh = (bf16)v;
        Oh[idx] = hh;
        Ol[idx] = (bf16)(v - (float)hh);
      }
}

// ---------------------------------------------------------------------------
// Kernel 3: plain bf16 GEMM for V; writes V transposed: [B,H,D,S]
// ---------------------------------------------------------------------------
__global__ __launch_bounds__(256) void gemm_v_kernel(
    const float* __restrict__ X, const bf16* __restrict__ Bth,
    bf16* __restrict__ Vt) {
  __shared__ bf16 sAh[128][40], sBh[128][40];
  const int n0 = blockIdx.x * 128, m0 = blockIdx.y * 128;
  const int tid = threadIdx.x;
  const int lane = tid & 63, w = tid >> 6;
  const int wm = (w >> 1) * 64, wn = (w & 1) * 64;
  const int fr = lane & 15, fg = lane >> 4, ko = fg * 8;
  f32x4 acc[4][4] = {};
  for (int k0 = 0; k0 < E_; k0 += 32) {
    __syncthreads();
#pragma unroll
    for (int i = 0; i < 4; ++i) {
      int lin = (tid + i * 256) * 4;
      int r = lin >> 5, c = lin & 31;
      f32x4 v = *(const f32x4*)&X[(size_t)(m0 + r) * E_ + k0 + c];
      bf16x4 hv;
#pragma unroll
      for (int j = 0; j < 4; ++j) hv[j] = (bf16)v[j];
      *(bf16x4*)&sAh[r][c] = hv;
    }
#pragma unroll
    for (int i = 0; i < 2; ++i) {
      int lin = (tid + i * 256) * 8;
      int r = lin >> 5, c = lin & 31;
      *(bf16x8*)&sBh[r][c] = *(const bf16x8*)&Bth[(size_t)(n0 + r) * E_ + k0 + c];
    }
    __syncthreads();
    bf16x8 ah[4];
#pragma unroll
    for (int mi = 0; mi < 4; ++mi)
      ah[mi] = *(const bf16x8*)&sAh[wm + mi * 16 + fr][ko];
#pragma unroll
    for (int ni = 0; ni < 4; ++ni) {
      bf16x8 bh = *(const bf16x8*)&sBh[wn + ni * 16 + fr][ko];
#pragma unroll
      for (int mi = 0; mi < 4; ++mi)
        acc[mi][ni] = mfma16(ah[mi], bh, acc[mi][ni]);
    }
  }
  // epilogue: pack 4 consecutive s per lane -> 8B store into Vt[B,H,D,S]
#pragma unroll
  for (int mi = 0; mi < 4; ++mi)
#pragma unroll
    for (int ni = 0; ni < 4; ++ni) {
      int row = m0 + wm + mi * 16 + fg * 4;       // base row (mult of 4)
      int col = n0 + wn + ni * 16 + fr;
      int bb = row >> 10, s = row & 1023;
      int hd = col >> 6, d = col & 63;
      bf16x4 p;
#pragma unroll
      for (int r = 0; r < 4; ++r) p[r] = (bf16)acc[mi][ni][r];
      *(bf16x4*)&Vt[((size_t)(bb * H_ + hd) * D_ + d) * S_ + s] = p;
    }
}

// ---------------------------------------------------------------------------
// Kernel 4: flash attention (no scale) + ReLU.
// Grid (S/64, H, B); 256 threads = 4 waves, each wave owns 16 q-rows.
// KV chunks of 64 staged in LDS.  QK^T uses 3-term split bf16 (fp32-accurate
// scores); online softmax in fp32; PV in plain bf16 via per-wave P LDS buffer.
// ---------------------------------------------------------------------------
__global__ __launch_bounds__(256) void attn_kernel(
    const bf16* __restrict__ Qh, const bf16* __restrict__ Ql,
    const bf16* __restrict__ Kh, const bf16* __restrict__ Kl,
    const bf16* __restrict__ Vt, float* __restrict__ out) {
  __shared__ bf16 sKh[64][72], sKl[64][72], sV[64][72];
  __shared__ bf16 sP[4][16][72];
  const int qb = blockIdx.x, hd = blockIdx.y, bb = blockIdx.z;
  const int tid = threadIdx.x;
  const int lane = tid & 63, w = tid >> 6;
  const int fr = lane & 15, fg = lane >> 4, ko = fg * 8;
  const size_t bh = (size_t)(bb * H_ + hd);
  const bf16* Qh_p = Qh + bh * (S_ * D_);
  const bf16* Ql_p = Ql + bh * (S_ * D_);
  const bf16* Kh_p = Kh + bh * (S_ * D_);
  const bf16* Kl_p = Kl + bh * (S_ * D_);
  const bf16* Vt_p = Vt + bh * (D_ * S_);
  const int q0 = qb * 64 + w * 16;

  // preload Q fragments (hi/lo, two 32-wide K-steps over D=64)
  bf16x8 qhf[2], qlf[2];
#pragma unroll
  for (int ks = 0; ks < 2; ++ks) {
    qhf[ks] = *(const bf16x8*)&Qh_p[(size_t)(q0 + fr) * D_ + ks * 32 + ko];
    qlf[ks] = *(const bf16x8*)&Ql_p[(size_t)(q0 + fr) * D_ + ks * 32 + ko];
  }

  float m_run[4] = {-1e30f, -1e30f, -1e30f, -1e30f};
  float l_run[4] = {0.f, 0.f, 0.f, 0.f};
  f32x4 O[4] = {};

  for (int kb = 0; kb < S_; kb += 64) {
    __syncthreads();  // all waves done reading previous K/V chunk
    // stage K hi/lo [64 keys][64 d] and V^T [64 d][64 keys]
#pragma unroll
    for (int i = 0; i < 2; ++i) {
      int lin = (tid + i * 256) * 8;
      int r = lin >> 6, c = lin & 63;
      *(bf16x8*)&sKh[r][c] = *(const bf16x8*)&Kh_p[(size_t)(kb + r) * D_ + c];
      *(bf16x8*)&sKl[r][c] = *(const bf16x8*)&Kl_p[(size_t)(kb + r) * D_ + c];
      *(bf16x8*)&sV[r][c]  = *(const bf16x8*)&Vt_p[(size_t)r * S_ + kb + c];
    }
    __syncthreads();

    // QK^T: 4 frags of 16 keys, 2 K-steps, 3-term split
    f32x4 sc[4] = {};
#pragma unroll
    for (int ks = 0; ks < 2; ++ks)
#pragma unroll
      for (int f = 0; f < 4; ++f) {
        bf16x8 kh = *(const bf16x8*)&sKh[f * 16 + fr][ks * 32 + ko];
        bf16x8 kl = *(const bf16x8*)&sKl[f * 16 + fr][ks * 32 + ko];
        sc[f] = mfma16(qhf[ks], kh, sc[f]);
        sc[f] = mfma16(qhf[ks], kl, sc[f]);
        sc[f] = mfma16(qlf[ks], kh, sc[f]);
      }

    // online softmax (rows r: q = fg*4 + r, cols: f*16 + fr)
#pragma unroll
    for (int r = 0; r < 4; ++r) {
      float mx = fmaxf(fmaxf(sc[0][r], sc[1][r]), fmaxf(sc[2][r], sc[3][r]));
#pragma unroll
      for (int off = 1; off < 16; off <<= 1)
        mx = fmaxf(mx, __shfl_xor(mx, off));
      float mn = fmaxf(m_run[r], mx);
      float scale = __expf(m_run[r] - mn);
      m_run[r] = mn;
      float rs = 0.f;
#pragma unroll
      for (int f = 0; f < 4; ++f) {
        float p = __expf(sc[f][r] - mn);
        rs += p;
        sP[w][fg * 4 + r][f * 16 + fr] = (bf16)p;
      }
#pragma unroll
      for (int off = 1; off < 16; off <<= 1)
        rs += __shfl_xor(rs, off);
      l_run[r] = l_run[r] * scale + rs;
      O[0][r] *= scale;
      O[1][r] *= scale;
      O[2][r] *= scale;
      O[3][r] *= scale;
    }
    // per-wave P buffer: compiler fence so PV reads see the writes
    asm volatile("" ::: "memory");

    // PV: O[16q x 64d] += P[16q x 64k] * V[64k x 64d]
#pragma unroll
    for (int c = 0; c < 2; ++c) {
      bf16x8 pa = *(const bf16x8*)&sP[w][fr][c * 32 + ko];
#pragma unroll
      for (int ni = 0; ni < 4; ++ni) {
        bf16x8 vb = *(const bf16x8*)&sV[ni * 16 + fr][c * 32 + ko];
        O[ni] = mfma16(pa, vb, O[ni]);
      }
    }
    asm volatile("" ::: "memory");
  }

  // epilogue: normalize, ReLU, write fp32 [B,S,E]
#pragma unroll
  for (int ni = 0; ni < 4; ++ni) {
#pragma unroll
    for (int r = 0; r < 4; ++r) {
      float v = O[ni][r] / l_run[r];
      v = fmaxf(v, 0.f);
      int s = q0 + fg * 4 + r;
      int e = hd * 64 + ni * 16 + fr;
      out[((size_t)bb * S_ + s) * E_ + e] = v;
    }
  }
}

// ---------------------------------------------------------------------------
// Host launcher.  Workspace layout (needs ~90.2 MB):
//   [0..2M)    Wqt_hi   [2M..4M)  Wqt_lo   [4M..6M)  Wkt_hi
//   [6M..8M)   Wkt_lo   [8M..10M) Wvt_hi
//   [10M..26M) Q_hi  [26M..42M) Q_lo  [42M..58M) K_hi  [58M..74M) K_lo
//   [74M..90M) Vt
// ---------------------------------------------------------------------------
extern "C" void kernel_launch(void* const* d_in, const int* in_sizes, int n_in,
                              void* d_out, int out_size, void* d_ws, size_t ws_size,
                              hipStream_t stream) {
  const float* X  = (const float*)d_in[0];
  const float* Wq = (const float*)d_in[1];
  const float* Wk = (const float*)d_in[2];
  const float* Wv = (const float*)d_in[3];
  float* out = (float*)d_out;
  char* ws = (char*)d_ws;

  const size_t WSZ = (size_t)E_ * E_ * sizeof(bf16);   // 2 MB
  const size_t QSZ = (size_t)M_ * E_ * sizeof(bf16);   // 16 MB
  bf16* Wqt_h = (bf16*)(ws);
  bf16* Wqt_l = (bf16*)(ws + WSZ);
  bf16* Wkt_h = (bf16*)(ws + 2 * WSZ);
  bf16* Wkt_l = (bf16*)(ws + 3 * WSZ);
  bf16* Wvt_h = (bf16*)(ws + 4 * WSZ);
  bf16* Qh = (bf16*)(ws + 5 * WSZ);
  bf16* Ql = (bf16*)(ws + 5 * WSZ + QSZ);
  bf16* Kh = (bf16*)(ws + 5 * WSZ + 2 * QSZ);
  bf16* Kl = (bf16*)(ws + 5 * WSZ + 3 * QSZ);
  bf16* Vt = (bf16*)(ws + 5 * WSZ + 4 * QSZ);

  dim3 tg(E_ / 64, E_ / 64);
  dim3 tb(64, 8);
  wt_conv_kernel<<<tg, tb, 0, stream>>>(Wq, Wqt_h, Wqt_l);
  wt_conv_kernel<<<tg, tb, 0, stream>>>(Wk, Wkt_h, Wkt_l);
  wt_conv_kernel<<<tg, tb, 0, stream>>>(Wv, Wvt_h, (bf16*)nullptr);

  dim3 gg(E_ / 128, M_ / 128);
  gemm_qk_kernel<<<gg, 256, 0, stream>>>(X, Wqt_h, Wqt_l, Qh, Ql);
  gemm_qk_kernel<<<gg, 256, 0, stream>>>(X, Wkt_h, Wkt_l, Kh, Kl);
  gemm_v_kernel<<<gg, 256, 0, stream>>>(X, Wvt_h, Vt);

  dim3 ag(S_ / 64, H_, B_);
  attn_kernel<<<ag, 256, 0, stream>>>(Qh, Ql, Kh, Kl, Vt, out);
}

// Round 2
// 286.727 us; speedup vs baseline: 1.1617x; 1.1617x over previous
//
#include <hip/hip_runtime.h>
#include <cstdint>
#include <cstddef>

// Problem constants (B,S,E fixed by the reference; H=16 heads, D=64)
#define B_ 8
#define S_ 1024
#define E_ 1024
#define H_ 16
#define D_ 64
#define M_ (B_*S_)   // 8192 rows of x

typedef __bf16 bf16;
typedef float  f32;
typedef __attribute__((ext_vector_type(8))) __bf16 bf16x8;
typedef __attribute__((ext_vector_type(4))) __bf16 bf16x4;
typedef __attribute__((ext_vector_type(4))) float  f32x4;
typedef __attribute__((ext_vector_type(16))) float f32x16;

__device__ __forceinline__ f32x4 mfma16(bf16x8 a, bf16x8 b, f32x4 c) {
  return __builtin_amdgcn_mfma_f32_16x16x32_bf16(a, b, c, 0, 0, 0);
}
__device__ __forceinline__ f32x16 mfma32(bf16x8 a, bf16x8 b, f32x16 c) {
  return __builtin_amdgcn_mfma_f32_32x32x16_bf16(a, b, c, 0, 0, 0);
}
// async global->LDS, 16B per lane; LDS dest must be uniform-base + lane*16
__device__ __forceinline__ void gll16(const bf16* g, bf16* l) {
  __builtin_amdgcn_global_load_lds(
      (const __attribute__((address_space(1))) void*)g,
      (__attribute__((address_space(3))) void*)l, 16, 0, 0);
}

// ---------------------------------------------------------------------------
// Kernel 1: transpose + split-convert a 1024x1024 fp32 weight into bf16
// hi/lo buffers, laid out transposed ([f][e]).  lo==nullptr -> hi only (W_V).
// ---------------------------------------------------------------------------
__global__ __launch_bounds__(512) void wt_conv_kernel(
    const float* __restrict__ W, bf16* __restrict__ hi, bf16* __restrict__ lo) {
  __shared__ float t[64][65];
  const int f0 = blockIdx.x * 64, e0 = blockIdx.y * 64;
  const int tx = threadIdx.x, ty = threadIdx.y;
#pragma unroll
  for (int j = 0; j < 8; ++j)
    t[ty + 8 * j][tx] = W[(size_t)(e0 + ty + 8 * j) * E_ + f0 + tx];
  __syncthreads();
#pragma unroll
  for (int j = 0; j < 8; ++j) {
    float v = t[tx][ty + 8 * j];
    bf16 hh = (bf16)v;
    size_t idx = (size_t)(f0 + ty + 8 * j) * E_ + e0 + tx;
    hi[idx] = hh;
    if (lo) lo[idx] = (bf16)(v - (float)hh);
  }
}

// ---------------------------------------------------------------------------
// Kernel 2: split-precision GEMM  O = X(fp32) * W  (W transposed, hi/lo).
// 3-term bf16 split => ~fp32-accurate scores downstream.
// Output hi/lo bf16 in [B,H,S,D].
// ---------------------------------------------------------------------------
__global__ __launch_bounds__(256) void gemm_qk_kernel(
    const float* __restrict__ X, const bf16* __restrict__ Bth,
    const bf16* __restrict__ Btl, bf16* __restrict__ Oh, bf16* __restrict__ Ol) {
  __shared__ bf16 sAh[128][40], sAl[128][40], sBh[128][40], sBl[128][40];
  const int n0 = blockIdx.x * 128, m0 = blockIdx.y * 128;
  const int tid = threadIdx.x;
  const int lane = tid & 63, w = tid >> 6;
  const int wm = (w >> 1) * 64, wn = (w & 1) * 64;
  const int fr = lane & 15, fg = lane >> 4, ko = fg * 8;
  f32x4 acc[4][4] = {};
  for (int k0 = 0; k0 < E_; k0 += 32) {
    __syncthreads();
#pragma unroll
    for (int i = 0; i < 4; ++i) {
      int lin = (tid + i * 256) * 4;
      int r = lin >> 5, c = lin & 31;
      f32x4 v = *(const f32x4*)&X[(size_t)(m0 + r) * E_ + k0 + c];
      bf16x4 hv, lv;
#pragma unroll
      for (int j = 0; j < 4; ++j) {
        bf16 hh = (bf16)v[j];
        hv[j] = hh;
        lv[j] = (bf16)(v[j] - (float)hh);
      }
      *(bf16x4*)&sAh[r][c] = hv;
      *(bf16x4*)&sAl[r][c] = lv;
    }
#pragma unroll
    for (int i = 0; i < 2; ++i) {
      int lin = (tid + i * 256) * 8;
      int r = lin >> 5, c = lin & 31;
      *(bf16x8*)&sBh[r][c] = *(const bf16x8*)&Bth[(size_t)(n0 + r) * E_ + k0 + c];
      *(bf16x8*)&sBl[r][c] = *(const bf16x8*)&Btl[(size_t)(n0 + r) * E_ + k0 + c];
    }
    __syncthreads();
    bf16x8 ah[4], al[4];
#pragma unroll
    for (int mi = 0; mi < 4; ++mi) {
      ah[mi] = *(const bf16x8*)&sAh[wm + mi * 16 + fr][ko];
      al[mi] = *(const bf16x8*)&sAl[wm + mi * 16 + fr][ko];
    }
#pragma unroll
    for (int ni = 0; ni < 4; ++ni) {
      bf16x8 bh = *(const bf16x8*)&sBh[wn + ni * 16 + fr][ko];
      bf16x8 bl = *(const bf16x8*)&sBl[wn + ni * 16 + fr][ko];
#pragma unroll
      for (int mi = 0; mi < 4; ++mi) {
        acc[mi][ni] = mfma16(ah[mi], bh, acc[mi][ni]);
        acc[mi][ni] = mfma16(ah[mi], bl, acc[mi][ni]);
        acc[mi][ni] = mfma16(al[mi], bh, acc[mi][ni]);
      }
    }
  }
#pragma unroll
  for (int mi = 0; mi < 4; ++mi)
#pragma unroll
    for (int ni = 0; ni < 4; ++ni)
#pragma unroll
      for (int r = 0; r < 4; ++r) {
        int row = m0 + wm + mi * 16 + fg * 4 + r;   // = b*1024 + s
        int col = n0 + wn + ni * 16 + fr;           // = hd*64 + d
        float v = acc[mi][ni][r];
        int bb = row >> 10, s = row & 1023;
        int hd = col >> 6, d = col & 63;
        size_t idx = ((size_t)(bb * H_ + hd) * S_ + s) * D_ + d;
        bf16 hh = (bf16)v;
        Oh[idx] = hh;
        Ol[idx] = (bf16)(v - (float)hh);
      }
}

// ---------------------------------------------------------------------------
// Kernel 3: plain bf16 GEMM for V; writes V transposed: [B,H,D,S]
// ---------------------------------------------------------------------------
__global__ __launch_bounds__(256) void gemm_v_kernel(
    const float* __restrict__ X, const bf16* __restrict__ Bth,
    bf16* __restrict__ Vt) {
  __shared__ bf16 sAh[128][40], sBh[128][40];
  const int n0 = blockIdx.x * 128, m0 = blockIdx.y * 128;
  const int tid = threadIdx.x;
  const int lane = tid & 63, w = tid >> 6;
  const int wm = (w >> 1) * 64, wn = (w & 1) * 64;
  const int fr = lane & 15, fg = lane >> 4, ko = fg * 8;
  f32x4 acc[4][4] = {};
  for (int k0 = 0; k0 < E_; k0 += 32) {
    __syncthreads();
#pragma unroll
    for (int i = 0; i < 4; ++i) {
      int lin = (tid + i * 256) * 4;
      int r = lin >> 5, c = lin & 31;
      f32x4 v = *(const f32x4*)&X[(size_t)(m0 + r) * E_ + k0 + c];
      bf16x4 hv;
#pragma unroll
      for (int j = 0; j < 4; ++j) hv[j] = (bf16)v[j];
      *(bf16x4*)&sAh[r][c] = hv;
    }
#pragma unroll
    for (int i = 0; i < 2; ++i) {
      int lin = (tid + i * 256) * 8;
      int r = lin >> 5, c = lin & 31;
      *(bf16x8*)&sBh[r][c] = *(const bf16x8*)&Bth[(size_t)(n0 + r) * E_ + k0 + c];
    }
    __syncthreads();
    bf16x8 ah[4];
#pragma unroll
    for (int mi = 0; mi < 4; ++mi)
      ah[mi] = *(const bf16x8*)&sAh[wm + mi * 16 + fr][ko];
#pragma unroll
    for (int ni = 0; ni < 4; ++ni) {
      bf16x8 bh = *(const bf16x8*)&sBh[wn + ni * 16 + fr][ko];
#pragma unroll
      for (int mi = 0; mi < 4; ++mi)
        acc[mi][ni] = mfma16(ah[mi], bh, acc[mi][ni]);
    }
  }
#pragma unroll
  for (int mi = 0; mi < 4; ++mi)
#pragma unroll
    for (int ni = 0; ni < 4; ++ni) {
      int row = m0 + wm + mi * 16 + fg * 4;
      int col = n0 + wn + ni * 16 + fr;
      int bb = row >> 10, s = row & 1023;
      int hd = col >> 6, d = col & 63;
      bf16x4 p;
#pragma unroll
      for (int r = 0; r < 4; ++r) p[r] = (bf16)acc[mi][ni][r];
      *(bf16x4*)&Vt[((size_t)(bb * H_ + hd) * D_ + d) * S_ + s] = p;
    }
}

// ---------------------------------------------------------------------------
// Kernel 4: flash attention (no scale) + ReLU  —  restructured.
// 4 waves x 64 q-rows = 256 q/block; 32x32x16 MFMA, swapped operands:
//   scores = mfma(K, Q)   -> lane owns query col (l&31): softmax in-lane + 1 shfl
//   O      = mfma(V^T, P) -> O cols match softmax lanes: no shuffles for rescale
// K hi/lo + V staged per 64-key chunk via global_load_lds with pre-swizzled
// source (XOR on 16B chunks by row&7) => conflict-free b128 fragment reads.
// P via per-wave swizzled LDS buffer (bf16x4 writes).
// Block-id swizzle: the 4 q-blocks of one (b,h) land on the same XCD.
// ---------------------------------------------------------------------------
__global__ __launch_bounds__(256) void attn_kernel(
    const bf16* __restrict__ Qh, const bf16* __restrict__ Ql,
    const bf16* __restrict__ Kh, const bf16* __restrict__ Kl,
    const bf16* __restrict__ Vt, float* __restrict__ out) {
  __shared__ bf16 sKh[64][64], sKl[64][64], sV[64][64];
  __shared__ bf16 sP[4][64][64];
  const int bid = blockIdx.x;
  const int bh = (bid & 7) + 8 * (bid >> 5);     // 0..127
  const int qb = (bid >> 3) & 3;
  const int hd = bh & 15, bb = bh >> 4;
  const int tid = threadIdx.x;
  const int lane = tid & 63, w = tid >> 6;
  const int cq = lane & 31, h = lane >> 5;       // query col, k-half
  const size_t base = (size_t)bh * (S_ * D_);
  const bf16* Qh_p = Qh + base;
  const bf16* Ql_p = Ql + base;
  const bf16* Kh_p = Kh + base;
  const bf16* Kl_p = Kl + base;
  const bf16* Vt_p = Vt + base;                  // [D][S] per head
  const int q0 = qb * 256 + w * 64;

  // persistent Q fragments: B-operand layout B[k=(l>>5)*8+j][l&31]
  bf16x8 qh_[2][4], ql_[2][4];
#pragma unroll
  for (int qf = 0; qf < 2; ++qf)
#pragma unroll
    for (int ks = 0; ks < 4; ++ks) {
      size_t off = (size_t)(q0 + qf * 32 + cq) * D_ + ks * 16 + 8 * h;
      qh_[qf][ks] = *(const bf16x8*)&Qh_p[off];
      ql_[qf][ks] = *(const bf16x8*)&Ql_p[off];
    }

  float m_run[2] = {-1e30f, -1e30f};
  float l_run[2] = {0.f, 0.f};
  f32x16 O[2][2] = {};

  for (int kb = 0; kb < S_; kb += 64) {
    __syncthreads();   // previous chunk fully consumed
    // stage K hi/lo [64k][64d] and V^T [64d][64k], source pre-swizzled
#pragma unroll
    for (int half = 0; half < 2; ++half) {
      int ci = tid + half * 256;
      int row = ci >> 3, cl = ci & 7;
      int cs = cl ^ (row & 7);
      gll16(Kh_p + (size_t)(kb + row) * D_ + cs * 8, &sKh[0][0] + ci * 8);
      gll16(Kl_p + (size_t)(kb + row) * D_ + cs * 8, &sKl[0][0] + ci * 8);
      gll16(Vt_p + (size_t)row * S_ + kb + cs * 8, &sV[0][0] + ci * 8);
    }
    __syncthreads();   // drains vmcnt before any lane reads

    // ---- QK^T (swapped): sc[qf][f] covers keys f*32..f*32+31 x 32 queries
    f32x16 sc[2][2] = {};
#pragma unroll
    for (int f = 0; f < 2; ++f)
#pragma unroll
      for (int ks = 0; ks < 4; ++ks) {
        int row = f * 32 + cq;
        int cc = ((2 * ks + h) ^ (cq & 7)) * 8;
        bf16x8 kh = *(const bf16x8*)&sKh[row][cc];
        bf16x8 kl = *(const bf16x8*)&sKl[row][cc];
#pragma unroll
        for (int qf = 0; qf < 2; ++qf) {
          sc[qf][f] = mfma32(kh, qh_[qf][ks], sc[qf][f]);
          sc[qf][f] = mfma32(kl, qh_[qf][ks], sc[qf][f]);
          sc[qf][f] = mfma32(kh, ql_[qf][ks], sc[qf][f]);
        }
      }

    // ---- online softmax per query (lane-local except 1 shfl across halves)
#pragma unroll
    for (int qf = 0; qf < 2; ++qf) {
      // pairwise max tree over the 32 in-lane scores
      float t8[8];
#pragma unroll
      for (int i = 0; i < 8; ++i)
        t8[i] = fmaxf(fmaxf(sc[qf][0][i], sc[qf][0][i + 8]),
                      fmaxf(sc[qf][1][i], sc[qf][1][i + 8]));
      float t4a = fmaxf(t8[0], t8[4]), t4b = fmaxf(t8[1], t8[5]);
      float t4c = fmaxf(t8[2], t8[6]), t4d = fmaxf(t8[3], t8[7]);
      float mx = fmaxf(fmaxf(t4a, t4b), fmaxf(t4c, t4d));
      mx = fmaxf(mx, __shfl_xor(mx, 32));
      float mn = fmaxf(m_run[qf], mx);
      float scale = __expf(m_run[qf] - mn);
      m_run[qf] = mn;
      float rs0 = 0.f, rs1 = 0.f, rs2 = 0.f, rs3 = 0.f;
      bf16x4 pk[8];
#pragma unroll
      for (int f = 0; f < 2; ++f)
#pragma unroll
        for (int r = 0; r < 16; ++r) {
          float p = __expf(sc[qf][f][r] - mn);
          if ((r & 3) == 0) rs0 += p;
          else if ((r & 3) == 1) rs1 += p;
          else if ((r & 3) == 2) rs2 += p;
          else rs3 += p;
          pk[f * 4 + (r >> 2)][r & 3] = (bf16)p;
        }
      float rs = (rs0 + rs1) + (rs2 + rs3);
      rs += __shfl_xor(rs, 32);
      l_run[qf] = l_run[qf] * scale + rs;
#pragma unroll
      for (int df = 0; df < 2; ++df)
#pragma unroll
        for (int i = 0; i < 16; ++i) O[qf][df][i] *= scale;
      // write P row (keys this lane owns: 4h + (r&3) + 8g + 32f), swizzled
      char* rowp = (char*)&sP[w][qf * 32 + cq][0];
#pragma unroll
      for (int f = 0; f < 2; ++f)
#pragma unroll
        for (int g = 0; g < 4; ++g) {
          int cw = ((g + 4 * f) ^ (cq & 7)) * 16 + 8 * h;
          *(bf16x4*)(rowp + cw) = pk[f * 4 + g];
        }
    }
    asm volatile("" ::: "memory");  // P writes before PV reads (same wave)

    // ---- PV (swapped): O[d][q] += V^T[d][k] * P[k][q]
#pragma unroll
    for (int ks = 0; ks < 4; ++ks) {
      bf16x8 pf[2];
#pragma unroll
      for (int qf = 0; qf < 2; ++qf) {
        int cc = ((2 * ks + h) ^ (cq & 7)) * 8;
        pf[qf] = *(const bf16x8*)&sP[w][qf * 32 + cq][cc];
      }
#pragma unroll
      for (int df = 0; df < 2; ++df) {
        int cc = ((2 * ks + h) ^ (cq & 7)) * 8;
        bf16x8 vf = *(const bf16x8*)&sV[df * 32 + cq][cc];
#pragma unroll
        for (int qf = 0; qf < 2; ++qf)
          O[qf][df] = mfma32(vf, pf[qf], O[qf][df]);
      }
    }
    asm volatile("" ::: "memory");
  }

  // ---- epilogue: v = relu(O/l), fp32 [B,S,E]; d = (r&3)+8*(r>>2)+4h+32df
#pragma unroll
  for (int qf = 0; qf < 2; ++qf) {
    float inv = 1.0f / l_run[qf];
    int s = q0 + qf * 32 + cq;
    float* orow = out + ((size_t)bb * S_ + s) * E_ + hd * 64;
#pragma unroll
    for (int df = 0; df < 2; ++df)
#pragma unroll
      for (int g = 0; g < 4; ++g) {
        f32x4 vv;
#pragma unroll
        for (int j = 0; j < 4; ++j)
          vv[j] = fmaxf(O[qf][df][4 * g + j] * inv, 0.f);
        *(f32x4*)&orow[df * 32 + 8 * g + 4 * h] = vv;
      }
  }
}

// ---------------------------------------------------------------------------
// Host launcher.  Workspace ~90.2 MB (same layout as before).
// ---------------------------------------------------------------------------
extern "C" void kernel_launch(void* const* d_in, const int* in_sizes, int n_in,
                              void* d_out, int out_size, void* d_ws, size_t ws_size,
                              hipStream_t stream) {
  const float* X  = (const float*)d_in[0];
  const float* Wq = (const float*)d_in[1];
  const float* Wk = (const float*)d_in[2];
  const float* Wv = (const float*)d_in[3];
  float* out = (float*)d_out;
  char* ws = (char*)d_ws;

  const size_t WSZ = (size_t)E_ * E_ * sizeof(bf16);   // 2 MB
  const size_t QSZ = (size_t)M_ * E_ * sizeof(bf16);   // 16 MB
  bf16* Wqt_h = (bf16*)(ws);
  bf16* Wqt_l = (bf16*)(ws + WSZ);
  bf16* Wkt_h = (bf16*)(ws + 2 * WSZ);
  bf16* Wkt_l = (bf16*)(ws + 3 * WSZ);
  bf16* Wvt_h = (bf16*)(ws + 4 * WSZ);
  bf16* Qh = (bf16*)(ws + 5 * WSZ);
  bf16* Ql = (bf16*)(ws + 5 * WSZ + QSZ);
  bf16* Kh = (bf16*)(ws + 5 * WSZ + 2 * QSZ);
  bf16* Kl = (bf16*)(ws + 5 * WSZ + 3 * QSZ);
  bf16* Vt = (bf16*)(ws + 5 * WSZ + 4 * QSZ);

  dim3 tg(E_ / 64, E_ / 64);
  dim3 tb(64, 8);
  wt_conv_kernel<<<tg, tb, 0, stream>>>(Wq, Wqt_h, Wqt_l);
  wt_conv_kernel<<<tg, tb, 0, stream>>>(Wk, Wkt_h, Wkt_l);
  wt_conv_kernel<<<tg, tb, 0, stream>>>(Wv, Wvt_h, (bf16*)nullptr);

  dim3 gg(E_ / 128, M_ / 128);
  gemm_qk_kernel<<<gg, 256, 0, stream>>>(X, Wqt_h, Wqt_l, Qh, Ql);
  gemm_qk_kernel<<<gg, 256, 0, stream>>>(X, Wkt_h, Wkt_l, Kh, Kl);
  gemm_v_kernel<<<gg, 256, 0, stream>>>(X, Wvt_h, Vt);

  attn_kernel<<<512, 256, 0, stream>>>(Qh, Ql, Kh, Kl, Vt, out);
}

// Round 3
// 242.546 us; speedup vs baseline: 1.3734x; 1.1822x over previous
//
#include <hip/hip_runtime.h>
#include <cstdint>
#include <cstddef>

#define B_ 8
#define S_ 1024
#define E_ 1024
#define H_ 16
#define D_ 64
#define M_ (B_*S_)

typedef __bf16 bf16;
typedef __attribute__((ext_vector_type(8))) __bf16 bf16x8;
typedef __attribute__((ext_vector_type(4))) __bf16 bf16x4;
typedef __attribute__((ext_vector_type(4))) float  f32x4;
typedef __attribute__((ext_vector_type(16))) float f32x16;
typedef __attribute__((ext_vector_type(4))) int    int4v;
typedef __attribute__((ext_vector_type(2))) int    int2v;

__device__ __forceinline__ f32x4 mfma16(bf16x8 a, bf16x8 b, f32x4 c) {
  return __builtin_amdgcn_mfma_f32_16x16x32_bf16(a, b, c, 0, 0, 0);
}
__device__ __forceinline__ f32x16 mfma32(bf16x8 a, bf16x8 b, f32x16 c) {
  return __builtin_amdgcn_mfma_f32_32x32x16_bf16(a, b, c, 0, 0, 0);
}
__device__ __forceinline__ void gll16(const bf16* g, bf16* l) {
  __builtin_amdgcn_global_load_lds(
      (const __attribute__((address_space(1))) void*)g,
      (__attribute__((address_space(3))) void*)l, 16, 0, 0);
}
__device__ __forceinline__ int cvtpk_bf16(float lo, float hi) {
  int r;
  asm("v_cvt_pk_bf16_f32 %0, %1, %2" : "=v"(r) : "v"(lo), "v"(hi));
  return r;
}

// ---------------------------------------------------------------------------
// Pre-split X fp32 -> bf16 hi/lo (memory-bound, ~64MB traffic)
// ---------------------------------------------------------------------------
__global__ __launch_bounds__(256) void presplit_kernel(
    const float* __restrict__ X, bf16* __restrict__ Xh, bf16* __restrict__ Xl) {
  size_t i = ((size_t)blockIdx.x * 256 + threadIdx.x) * 8;
  f32x4 v0 = *(const f32x4*)&X[i];
  f32x4 v1 = *(const f32x4*)&X[i + 4];
  bf16x8 hv, lv;
#pragma unroll
  for (int j = 0; j < 4; ++j) {
    bf16 h0 = (bf16)v0[j];
    hv[j] = h0; lv[j] = (bf16)(v0[j] - (float)h0);
    bf16 h1 = (bf16)v1[j];
    hv[j + 4] = h1; lv[j + 4] = (bf16)(v1[j] - (float)h1);
  }
  *(bf16x8*)&Xh[i] = hv;
  *(bf16x8*)&Xl[i] = lv;
}

// ---------------------------------------------------------------------------
// Transpose + split-convert all 3 weights in one launch (z selects weight)
// ---------------------------------------------------------------------------
__global__ __launch_bounds__(512) void wt_conv3_kernel(
    const float* __restrict__ Wq, const float* __restrict__ Wk,
    const float* __restrict__ Wv, bf16* __restrict__ qh, bf16* __restrict__ ql,
    bf16* __restrict__ kh, bf16* __restrict__ kl, bf16* __restrict__ vh) {
  const float* W = blockIdx.z == 0 ? Wq : (blockIdx.z == 1 ? Wk : Wv);
  bf16* hi = blockIdx.z == 0 ? qh : (blockIdx.z == 1 ? kh : vh);
  bf16* lo = blockIdx.z == 0 ? ql : (blockIdx.z == 1 ? kl : (bf16*)nullptr);
  __shared__ float t[64][65];
  const int f0 = blockIdx.x * 64, e0 = blockIdx.y * 64;
  const int tx = threadIdx.x, ty = threadIdx.y;
#pragma unroll
  for (int j = 0; j < 8; ++j)
    t[ty + 8 * j][tx] = W[(size_t)(e0 + ty + 8 * j) * E_ + f0 + tx];
  __syncthreads();
#pragma unroll
  for (int j = 0; j < 8; ++j) {
    float v = t[tx][ty + 8 * j];
    bf16 hh = (bf16)v;
    size_t idx = (size_t)(f0 + ty + 8 * j) * E_ + e0 + tx;
    hi[idx] = hh;
    if (lo) lo[idx] = (bf16)(v - (float)hh);
  }
}

// ---------------------------------------------------------------------------
// Split-precision GEMM (m97-style): O = (Xh+Xl) * (Wh+Wl), 3-term.
// All-bf16 inputs staged via global_load_lds w=16 (no VALU convert).
// BM=BN=128, BK=32, 4 waves, 48 mfma16/wave/step. Output hi/lo -> [B,H,S,D].
// ---------------------------------------------------------------------------
__global__ __launch_bounds__(256) void gemm_qk2_kernel(
    const bf16* __restrict__ Xh, const bf16* __restrict__ Xl,
    const bf16* __restrict__ Bth, const bf16* __restrict__ Btl,
    bf16* __restrict__ Oh, bf16* __restrict__ Ol) {
  __shared__ bf16 sAh[128][32], sAl[128][32], sBh[128][32], sBl[128][32];
  const int n0 = blockIdx.x * 128, m0 = blockIdx.y * 128;
  const int tid = threadIdx.x;
  const int lane = tid & 63, w = tid >> 6;
  const int wm = (w >> 1) * 64, wn = (w & 1) * 64;
  const int fr = lane & 15, fg = lane >> 4, ko = fg * 8;
  f32x4 acc[4][4] = {};
  for (int k0 = 0; k0 < E_; k0 += 32) {
#pragma unroll
    for (int i = 0; i < 2; ++i) {
      int ci = tid + i * 256;            // 512 chunks of 16B per 8KB tile
      int r = ci >> 2, c = (ci & 3) * 8;
      gll16(Xh  + (size_t)(m0 + r) * E_ + k0 + c, &sAh[0][0] + ci * 8);
      gll16(Xl  + (size_t)(m0 + r) * E_ + k0 + c, &sAl[0][0] + ci * 8);
      gll16(Bth + (size_t)(n0 + r) * E_ + k0 + c, &sBh[0][0] + ci * 8);
      gll16(Btl + (size_t)(n0 + r) * E_ + k0 + c, &sBl[0][0] + ci * 8);
    }
    __syncthreads();   // drains vmcnt -> staged tile visible to all
    bf16x8 ah[4], al[4];
#pragma unroll
    for (int mi = 0; mi < 4; ++mi) {
      ah[mi] = *(const bf16x8*)&sAh[wm + mi * 16 + fr][ko];
      al[mi] = *(const bf16x8*)&sAl[wm + mi * 16 + fr][ko];
    }
#pragma unroll
    for (int ni = 0; ni < 4; ++ni) {
      bf16x8 bh = *(const bf16x8*)&sBh[wn + ni * 16 + fr][ko];
      bf16x8 bl = *(const bf16x8*)&sBl[wn + ni * 16 + fr][ko];
#pragma unroll
      for (int mi = 0; mi < 4; ++mi) {
        acc[mi][ni] = mfma16(ah[mi], bh, acc[mi][ni]);
        acc[mi][ni] = mfma16(ah[mi], bl, acc[mi][ni]);
        acc[mi][ni] = mfma16(al[mi], bh, acc[mi][ni]);
      }
    }
    __syncthreads();   // compute done before next stage overwrites
  }
#pragma unroll
  for (int mi = 0; mi < 4; ++mi)
#pragma unroll
    for (int ni = 0; ni < 4; ++ni)
#pragma unroll
      for (int r = 0; r < 4; ++r) {
        int row = m0 + wm + mi * 16 + fg * 4 + r;
        int col = n0 + wn + ni * 16 + fr;
        float v = acc[mi][ni][r];
        int bb = row >> 10, s = row & 1023;
        int hd = col >> 6, d = col & 63;
        size_t idx = ((size_t)(bb * H_ + hd) * S_ + s) * D_ + d;
        bf16 hh = (bf16)v;
        Oh[idx] = hh;
        Ol[idx] = (bf16)(v - (float)hh);
      }
}

// ---------------------------------------------------------------------------
// Plain bf16 GEMM for V (m97-style), writes V^T [B,H,D,S]
// ---------------------------------------------------------------------------
__global__ __launch_bounds__(256) void gemm_v2_kernel(
    const bf16* __restrict__ Xh, const bf16* __restrict__ Bth,
    bf16* __restrict__ Vt) {
  __shared__ bf16 sA[128][32], sB[128][32];
  const int n0 = blockIdx.x * 128, m0 = blockIdx.y * 128;
  const int tid = threadIdx.x;
  const int lane = tid & 63, w = tid >> 6;
  const int wm = (w >> 1) * 64, wn = (w & 1) * 64;
  const int fr = lane & 15, fg = lane >> 4, ko = fg * 8;
  f32x4 acc[4][4] = {};
  for (int k0 = 0; k0 < E_; k0 += 32) {
#pragma unroll
    for (int i = 0; i < 2; ++i) {
      int ci = tid + i * 256;
      int r = ci >> 2, c = (ci & 3) * 8;
      gll16(Xh  + (size_t)(m0 + r) * E_ + k0 + c, &sA[0][0] + ci * 8);
      gll16(Bth + (size_t)(n0 + r) * E_ + k0 + c, &sB[0][0] + ci * 8);
    }
    __syncthreads();
    bf16x8 ah[4];
#pragma unroll
    for (int mi = 0; mi < 4; ++mi)
      ah[mi] = *(const bf16x8*)&sA[wm + mi * 16 + fr][ko];
#pragma unroll
    for (int ni = 0; ni < 4; ++ni) {
      bf16x8 bh = *(const bf16x8*)&sB[wn + ni * 16 + fr][ko];
#pragma unroll
      for (int mi = 0; mi < 4; ++mi)
        acc[mi][ni] = mfma16(ah[mi], bh, acc[mi][ni]);
    }
    __syncthreads();
  }
#pragma unroll
  for (int mi = 0; mi < 4; ++mi)
#pragma unroll
    for (int ni = 0; ni < 4; ++ni) {
      int row = m0 + wm + mi * 16 + fg * 4;
      int col = n0 + wn + ni * 16 + fr;
      int bb = row >> 10, s = row & 1023;
      int hd = col >> 6, d = col & 63;
      bf16x4 p;
#pragma unroll
      for (int r = 0; r < 4; ++r) p[r] = (bf16)acc[mi][ni][r];
      *(bf16x4*)&Vt[((size_t)(bb * H_ + hd) * D_ + d) * S_ + s] = p;
    }
}

// ---------------------------------------------------------------------------
// Flash attention + ReLU: double-buffered K/V staging (counted vmcnt),
// T12 in-register P (cvt_pk + permlane32_swap), no P LDS buffer.
// ---------------------------------------------------------------------------
__global__ __launch_bounds__(256, 2) void attn_kernel(
    const bf16* __restrict__ Qh, const bf16* __restrict__ Ql,
    const bf16* __restrict__ Kh, const bf16* __restrict__ Kl,
    const bf16* __restrict__ Vt, float* __restrict__ out) {
  __shared__ bf16 sKh[2][64][64], sKl[2][64][64], sV[2][64][64];
  const int bid = blockIdx.x;
  const int bh = (bid & 7) + 8 * (bid >> 5);
  const int qb = (bid >> 3) & 3;
  const int hd = bh & 15, bb = bh >> 4;
  const int tid = threadIdx.x;
  const int lane = tid & 63, w = tid >> 6;
  const int cq = lane & 31, h = lane >> 5;
  const size_t base = (size_t)bh * (S_ * D_);
  const bf16* Qh_p = Qh + base;
  const bf16* Ql_p = Ql + base;
  const bf16* Kh_p = Kh + base;
  const bf16* Kl_p = Kl + base;
  const bf16* Vt_p = Vt + base;
  const int q0 = qb * 256 + w * 64;

  bf16x8 qh_[2][4], ql_[2][4];
#pragma unroll
  for (int qf = 0; qf < 2; ++qf)
#pragma unroll
    for (int ks = 0; ks < 4; ++ks) {
      size_t off = (size_t)(q0 + qf * 32 + cq) * D_ + ks * 16 + 8 * h;
      qh_[qf][ks] = *(const bf16x8*)&Qh_p[off];
      ql_[qf][ks] = *(const bf16x8*)&Ql_p[off];
    }

  float m_run[2] = {-1e30f, -1e30f};
  float l_run[2] = {0.f, 0.f};
  f32x16 O[2][2] = {};

#define STAGE(buf, kb)                                                        \
  {                                                                           \
    _Pragma("unroll")                                                         \
    for (int half = 0; half < 2; ++half) {                                    \
      int ci = tid + half * 256;                                              \
      int row = ci >> 3, cl = ci & 7;                                         \
      int cs = cl ^ (row & 7);                                                \
      gll16(Kh_p + (size_t)((kb) + row) * D_ + cs * 8, &sKh[buf][0][0] + ci * 8); \
      gll16(Kl_p + (size_t)((kb) + row) * D_ + cs * 8, &sKl[buf][0][0] + ci * 8); \
      gll16(Vt_p + (size_t)row * S_ + (kb) + cs * 8, &sV[buf][0][0] + ci * 8);    \
    }                                                                         \
  }

  STAGE(0, 0);
  int cur = 0;
  for (int t = 0; t < 16; ++t) {
    __builtin_amdgcn_s_barrier();          // all waves done with buf cur^1
    if (t < 15) {
      STAGE(cur ^ 1, (t + 1) * 64);        // prefetch next chunk
      asm volatile("s_waitcnt vmcnt(6)" ::: "memory");  // current chunk ready
    } else {
      asm volatile("s_waitcnt vmcnt(0)" ::: "memory");
    }
    __builtin_amdgcn_sched_barrier(0);
    __builtin_amdgcn_s_barrier();          // everyone's staging visible

    // ---- QK^T (swapped): sc[qf][f] = scores for keys f*32.., queries cq
    f32x16 sc[2][2] = {};
    __builtin_amdgcn_s_setprio(1);
#pragma unroll
    for (int f = 0; f < 2; ++f)
#pragma unroll
      for (int ks = 0; ks < 4; ++ks) {
        int row = f * 32 + cq;
        int cc = ((2 * ks + h) ^ (cq & 7)) * 8;
        bf16x8 kh = *(const bf16x8*)&sKh[cur][row][cc];
        bf16x8 kl = *(const bf16x8*)&sKl[cur][row][cc];
#pragma unroll
        for (int qf = 0; qf < 2; ++qf) {
          sc[qf][f] = mfma32(kh, qh_[qf][ks], sc[qf][f]);
          sc[qf][f] = mfma32(kl, qh_[qf][ks], sc[qf][f]);
          sc[qf][f] = mfma32(kh, ql_[qf][ks], sc[qf][f]);
        }
      }
    __builtin_amdgcn_s_setprio(0);

    // ---- online softmax (in-lane; 1 shfl across halves) + T12 P-fragments
    bf16x8 pf[2][4];
#pragma unroll
    for (int qf = 0; qf < 2; ++qf) {
      float t8[8];
#pragma unroll
      for (int i = 0; i < 8; ++i)
        t8[i] = fmaxf(fmaxf(sc[qf][0][i], sc[qf][0][i + 8]),
                      fmaxf(sc[qf][1][i], sc[qf][1][i + 8]));
      float t4a = fmaxf(t8[0], t8[4]), t4b = fmaxf(t8[1], t8[5]);
      float t4c = fmaxf(t8[2], t8[6]), t4d = fmaxf(t8[3], t8[7]);
      float mx = fmaxf(fmaxf(t4a, t4b), fmaxf(t4c, t4d));
      mx = fmaxf(mx, __shfl_xor(mx, 32));
      float mn = fmaxf(m_run[qf], mx);
      float scale = __expf(m_run[qf] - mn);
      m_run[qf] = mn;
      float rs0 = 0.f, rs1 = 0.f, rs2 = 0.f, rs3 = 0.f;
#pragma unroll
      for (int f = 0; f < 2; ++f)
#pragma unroll
        for (int r = 0; r < 16; ++r) {
          float p = __expf(sc[qf][f][r] - mn);
          if ((r & 3) == 0) rs0 += p;
          else if ((r & 3) == 1) rs1 += p;
          else if ((r & 3) == 2) rs2 += p;
          else rs3 += p;
          sc[qf][f][r] = p;               // reuse sc as P storage
        }
      float rs = (rs0 + rs1) + (rs2 + rs3);
      rs += __shfl_xor(rs, 32);
      l_run[qf] = l_run[qf] * scale + rs;
#pragma unroll
      for (int df = 0; df < 2; ++df)
#pragma unroll
        for (int i = 0; i < 16; ++i) O[qf][df][i] *= scale;
      // build PV B-fragments in-register: pf[ks][j] = P[16ks+8h+j][cq]
#pragma unroll
      for (int f = 0; f < 2; ++f)
#pragma unroll
        for (int ksl = 0; ksl < 2; ++ksl) {
          int b0 = 8 * ksl;
          int a1 = cvtpk_bf16(sc[qf][f][b0 + 0], sc[qf][f][b0 + 1]);
          int b1 = cvtpk_bf16(sc[qf][f][b0 + 4], sc[qf][f][b0 + 5]);
          int2v r1 = __builtin_amdgcn_permlane32_swap(a1, b1, false, false);
          int a2 = cvtpk_bf16(sc[qf][f][b0 + 2], sc[qf][f][b0 + 3]);
          int b2 = cvtpk_bf16(sc[qf][f][b0 + 6], sc[qf][f][b0 + 7]);
          int2v r2 = __builtin_amdgcn_permlane32_swap(a2, b2, false, false);
          int4v wd;
          wd[0] = r1[0]; wd[1] = r2[0]; wd[2] = r1[1]; wd[3] = r2[1];
          pf[qf][2 * f + ksl] = __builtin_bit_cast(bf16x8, wd);
        }
    }

    // ---- PV (swapped): O[d][q] += V^T[d][k] * P[k][q]
    __builtin_amdgcn_s_setprio(1);
#pragma unroll
    for (int ks = 0; ks < 4; ++ks) {
      int cc = ((2 * ks + h) ^ (cq & 7)) * 8;
#pragma unroll
      for (int df = 0; df < 2; ++df) {
        bf16x8 vf = *(const bf16x8*)&sV[cur][df * 32 + cq][cc];
        O[0][df] = mfma32(vf, pf[0][ks], O[0][df]);
        O[1][df] = mfma32(vf, pf[1][ks], O[1][df]);
      }
    }
    __builtin_amdgcn_s_setprio(0);
    cur ^= 1;
  }

  // ---- epilogue: relu(O/l) -> fp32 [B,S,E]
#pragma unroll
  for (int qf = 0; qf < 2; ++qf) {
    float inv = 1.0f / l_run[qf];
    int s = q0 + qf * 32 + cq;
    float* orow = out + ((size_t)bb * S_ + s) * E_ + hd * 64;
#pragma unroll
    for (int df = 0; df < 2; ++df)
#pragma unroll
      for (int g = 0; g < 4; ++g) {
        f32x4 vv;
#pragma unroll
        for (int j = 0; j < 4; ++j)
          vv[j] = fmaxf(O[qf][df][4 * g + j] * inv, 0.f);
        *(f32x4*)&orow[df * 32 + 8 * g + 4 * h] = vv;
      }
  }
}

// ---------------------------------------------------------------------------
// Launcher. Workspace ~122 MB:
//  W bufs 5x2MB @0; Xh @10M; Xl @26M; Qh @42M; Ql @58M; Kh @74M; Kl @90M; Vt @106M
// ---------------------------------------------------------------------------
extern "C" void kernel_launch(void* const* d_in, const int* in_sizes, int n_in,
                              void* d_out, int out_size, void* d_ws, size_t ws_size,
                              hipStream_t stream) {
  const float* X  = (const float*)d_in[0];
  const float* Wq = (const float*)d_in[1];
  const float* Wk = (const float*)d_in[2];
  const float* Wv = (const float*)d_in[3];
  float* out = (float*)d_out;
  char* ws = (char*)d_ws;

  const size_t WSZ = (size_t)E_ * E_ * sizeof(bf16);   // 2 MB
  const size_t QSZ = (size_t)M_ * E_ * sizeof(bf16);   // 16 MB
  bf16* Wqt_h = (bf16*)(ws);
  bf16* Wqt_l = (bf16*)(ws + WSZ);
  bf16* Wkt_h = (bf16*)(ws + 2 * WSZ);
  bf16* Wkt_l = (bf16*)(ws + 3 * WSZ);
  bf16* Wvt_h = (bf16*)(ws + 4 * WSZ);
  char* p = ws + 5 * WSZ;
  bf16* Xh = (bf16*)(p);
  bf16* Xl = (bf16*)(p + QSZ);
  bf16* Qh = (bf16*)(p + 2 * QSZ);
  bf16* Ql = (bf16*)(p + 3 * QSZ);
  bf16* Kh = (bf16*)(p + 4 * QSZ);
  bf16* Kl = (bf16*)(p + 5 * QSZ);
  bf16* Vt = (bf16*)(p + 6 * QSZ);

  presplit_kernel<<<4096, 256, 0, stream>>>(X, Xh, Xl);
  wt_conv3_kernel<<<dim3(16, 16, 3), dim3(64, 8), 0, stream>>>(
      Wq, Wk, Wv, Wqt_h, Wqt_l, Wkt_h, Wkt_l, Wvt_h);

  dim3 gg(E_ / 128, M_ / 128);
  gemm_qk2_kernel<<<gg, 256, 0, stream>>>(Xh, Xl, Wqt_h, Wqt_l, Qh, Ql);
  gemm_qk2_kernel<<<gg, 256, 0, stream>>>(Xh, Xl, Wkt_h, Wkt_l, Kh, Kl);
  gemm_v2_kernel<<<gg, 256, 0, stream>>>(Xh, Wvt_h, Vt);

  attn_kernel<<<512, 256, 0, stream>>>(Qh, Ql, Kh, Kl, Vt, out);
}